// Round 4
// baseline (3817.464 us; speedup 1.0000x reference)
//
#include <hip/hip_runtime.h>

// GRU scan, pair-split persistent kernel. B=512, S=1024, I=64, H=256, G=768.
// 64 blocks x 512 threads. Block b: g = b&31 (batch rows 16g..16g+15),
// half = b>>5 (h-cols [128*half, 128*half+128)). Pair (g, g+32) exchanges h
// halves each step via L2/L3 with device-scope release/acquire flags.
// ALL weights live in registers (per wave: 3 Wh tiles + 6 Wx frags = 120 regs).
// Weights/bias pre-scaled by log2e (n-gate: 2*log2e) so gates use native
// v_exp_f32 (exp2) with the negate folded into the input modifier.

typedef short v8s __attribute__((ext_vector_type(8)));   // 8 bf16
typedef float f32x4 __attribute__((ext_vector_type(4)));

#define LOG2E 1.4426950408889634f
#define WS_FLAGS_OFF 0
#define WS_XCHG_OFF  4096
#define WS_NEED      (4096 + 2 * 32 * 2 * 4096)   // flags + xchg[2][32][2][4KB]

__device__ __forceinline__ unsigned short f2b(float f) {
    unsigned int u = __float_as_uint(f);
    u += 0x7FFFu + ((u >> 16) & 1u);       // RNE
    return (unsigned short)(u >> 16);
}
__device__ __forceinline__ float b2f(unsigned short h) {
    return __uint_as_float(((unsigned int)h) << 16);
}
__device__ __forceinline__ v8s cvt8(f32x4 a, f32x4 b) {
    v8s r;
#pragma unroll
    for (int j = 0; j < 4; ++j) { r[j] = (short)f2b(a[j]); r[4 + j] = (short)f2b(b[j]); }
    return r;
}
__device__ __forceinline__ float rcpf(float v) {
#if __has_builtin(__builtin_amdgcn_rcpf)
    return __builtin_amdgcn_rcpf(v);
#else
    return 1.0f / v;
#endif
}
__device__ __forceinline__ float exp2f_(float v) {
#if __has_builtin(__builtin_amdgcn_exp2f)
    return __builtin_amdgcn_exp2f(v);
#else
    return __exp2f(v);
#endif
}
// sigmoid of already-log2e-scaled preactivation v': sigma = 1/(1+2^-v')
__device__ __forceinline__ float sg(float v) { return rcpf(1.0f + exp2f_(-v)); }

__device__ __forceinline__ f32x4 MF(v8s a, v8s b, f32x4 c) {
    return __builtin_amdgcn_mfma_f32_16x16x32_bf16(a, b, c, 0, 0, 0);
}
// A-frag order index for element (row, k): u16 units
__device__ __forceinline__ int fidx(int row, int k) {
    return ((k >> 5) << 9) + ((((k >> 3) & 3) << 4) + row) * 8 + (k & 7);
}
__device__ __forceinline__ v8s wfrag(const float* src, float s) {
    f32x4 a = *(const f32x4*)src, b = *(const f32x4*)(src + 4);
    a *= s; b *= s;
    return cvt8(a, b);
}

extern "C" __global__ void __launch_bounds__(512, 2)
gru_pair(const float* __restrict__ x, const float* __restrict__ Wx,
         const float* __restrict__ Wh, const float* __restrict__ bias,
         const float* __restrict__ fcw, const float* __restrict__ fcb,
         float* __restrict__ out, char* __restrict__ ws)
{
    __shared__ char s_h[2][8192];   // full h as 8 ks-frags, ping-pong
    __shared__ char s_x[2][2048];   // x_t as 2 ks-frags, ping-pong

    const int tid = threadIdx.x;
    const int w = tid >> 6, l = tid & 63;
    const int cl = l & 15, kg = l >> 4;
    const int g = blockIdx.x & 31, half = blockIdx.x >> 5;
    const int b0 = g << 4;

    int* flags = (int*)(ws + WS_FLAGS_OFF);
    char* xch  = ws + WS_XCHG_OFF;
    int* myflag = flags + ((g << 1) | half);
    int* pflag  = flags + ((g << 1) | (half ^ 1));
    // xchg buffer (parity p, this g, writer-half hf): 4KB image of 4 ks-frags
    auto xbuf = [&](int p, int hf) -> char* {
        return xch + ((((p << 5) | g) << 1) | hf) * 4096;
    };

    // ---- weight fragments, all resident (120 regs) ----
    const int tr = 8 * half + w, tz = 16 + tr, tn = 32 + tr;
    v8s whR[8], whZ[8], whN[8], wxR[2], wxZ[2], wxN[2];
    {
        const float* sr = Wh + (size_t)(tr * 16 + cl) * 256 + kg * 8;
        const float* sz = Wh + (size_t)(tz * 16 + cl) * 256 + kg * 8;
        const float* sn = Wh + (size_t)(tn * 16 + cl) * 256 + kg * 8;
#pragma unroll
        for (int ks = 0; ks < 8; ++ks) {
            whR[ks] = wfrag(sr + ks * 32, LOG2E);
            whZ[ks] = wfrag(sz + ks * 32, LOG2E);
            whN[ks] = wfrag(sn + ks * 32, 2.0f * LOG2E);
        }
        const float* xr_ = Wx + (size_t)(tr * 16 + cl) * 64 + kg * 8;
        const float* xz_ = Wx + (size_t)(tz * 16 + cl) * 64 + kg * 8;
        const float* xn_ = Wx + (size_t)(tn * 16 + cl) * 64 + kg * 8;
#pragma unroll
        for (int k2 = 0; k2 < 2; ++k2) {
            wxR[k2] = wfrag(xr_ + k2 * 32, LOG2E);
            wxZ[k2] = wfrag(xz_ + k2 * 32, LOG2E);
            wxN[k2] = wfrag(xn_ + k2 * 32, 2.0f * LOG2E);
        }
    }

    // lane's output column (C-layout col == l&15 == cl), pre-scaled biases
    const int col = half * 128 + w * 16 + cl;
    const float br = bias[col] * LOG2E;
    const float bz = bias[256 + col] * LOG2E;
    const float bh = bias[512 + col] * (2.0f * LOG2E);
    const int base16 = ((col >> 5) << 9) + (((col >> 3) & 3) << 7) + (col & 7);
    const int img16  = base16 - (half << 11);          // offset in 4KB exchange image
    const int ownks0 = half << 2;                      // own frags: ks in [ownks0, ownks0+4)

    // ---- prologue: h0 = 0, stage x_0 ----
    for (int i = tid; i < 2048; i += 512) ((unsigned int*)s_h[0])[i] = 0u;
    const int xr = tid >> 5, xc = (tid & 31) << 1;
    const int xidx = fidx(xr, xc);
    const float* xp = x + (((size_t)(b0 + xr)) << 16) + xc;
    {
        unsigned int pk = (unsigned int)f2b(xp[0]) | ((unsigned int)f2b(xp[1]) << 16);
        *(unsigned int*)(s_x[0] + xidx * 2) = pk;
    }
    xp += 64;
    float hprev[4] = {0.0f, 0.0f, 0.0f, 0.0f};
    __syncthreads();

    // ================= scan =================
    for (int t = 0; t < 1024; ++t) {
        const int cur = t & 1, nxt = cur ^ 1;
        const v8s* hb = (const v8s*)s_h[cur];
        const v8s* xb = (const v8s*)s_x[cur];

        // prefetch x(t+1)
        float xv0 = 0.0f, xv1 = 0.0f;
        if (t < 1023) { xv0 = xp[0]; xv1 = xp[1]; xp += 64; }

        f32x4 aR = {0,0,0,0}, aZ = {0,0,0,0}, aNh = {0,0,0,0}, aNx = {0,0,0,0};

        // ---- (A) own-half K + x phase (no partner dependency) ----
#pragma unroll
        for (int j = 0; j < 4; ++j) {
            v8s a = hb[((ownks0 + j) << 6) + l];
            aR = MF(a, whR[ownks0 + j], aR);
            aZ = MF(a, whZ[ownks0 + j], aZ);
            aNh = MF(a, whN[ownks0 + j], aNh);
        }
#pragma unroll
        for (int k2 = 0; k2 < 2; ++k2) {
            v8s ax = xb[(k2 << 6) + l];
            aR = MF(ax, wxR[k2], aR);
            aZ = MF(ax, wxZ[k2], aZ);
            aNx = MF(ax, wxN[k2], aNx);
        }

        // ---- (S) wave0: acquire partner h_t half, copy into s_h[cur] ----
        if (t > 0 && w == 0) {
            while (__hip_atomic_load(pflag, __ATOMIC_ACQUIRE, __HIP_MEMORY_SCOPE_AGENT) < t)
                __builtin_amdgcn_s_sleep(1);
            const char* src = xbuf(t & 1, half ^ 1);
            char* dst = s_h[cur] + ((half ^ 1) << 12);   // partner frag base (4KB)
#pragma unroll
            for (int j = 0; j < 4; ++j)
                *(f32x4*)(dst + j * 1024 + l * 16) = *(const f32x4*)(src + j * 1024 + l * 16);
        }
        __syncthreads();

        // ---- (B) partner-half K ----
        const int oks0 = ownks0 ^ 4;
#pragma unroll
        for (int j = 0; j < 4; ++j) {
            v8s a = hb[((oks0 + j) << 6) + l];
            aR = MF(a, whR[oks0 + j], aR);
            aZ = MF(a, whZ[oks0 + j], aZ);
            aNh = MF(a, whN[oks0 + j], aNh);
        }

        // ---- (E) elementwise -> own half of h_{t+1}; LDS + exchange image ----
        unsigned short* hn = (unsigned short*)s_h[nxt];
        unsigned short* xo = (unsigned short*)xbuf(nxt, half);
#pragma unroll
        for (int i = 0; i < 4; ++i) {
            float rg = sg(aR[i] + br);
            float zg = sg(aZ[i] + bz);
            float ng = __builtin_fmaf(2.0f, sg(aNx[i] + bh + rg * aNh[i]), -1.0f);
            float hy = ng + zg * (hprev[i] - ng);
            hprev[i] = hy;
            unsigned short hv = f2b(hy);
            int off = base16 + ((kg << 2) + i) * 8;
            hn[off] = hv;
            xo[img16 + ((kg << 2) + i) * 8] = hv;
        }
        // stage x(t+1)
        if (t < 1023) {
            unsigned int pk = (unsigned int)f2b(xv0) | ((unsigned int)f2b(xv1) << 16);
            *(unsigned int*)(s_x[nxt] + xidx * 2) = pk;
        }
        __syncthreads();    // LDS writes visible; global stores vmcnt-drained
        if (tid == 0)
            __hip_atomic_store(myflag, t + 1, __ATOMIC_RELEASE, __HIP_MEMORY_SCOPE_AGENT);
    }

    // ---- epilogue: half 0 assembles full h_1024 and writes logits ----
    if (half == 0) {
        if (w == 0) {
            while (__hip_atomic_load(pflag, __ATOMIC_ACQUIRE, __HIP_MEMORY_SCOPE_AGENT) < 1024)
                __builtin_amdgcn_s_sleep(1);
            const char* src = xbuf(0, 1);
            char* dst = s_h[0] + 4096;
#pragma unroll
            for (int j = 0; j < 4; ++j)
                *(f32x4*)(dst + j * 1024 + l * 16) = *(const f32x4*)(src + j * 1024 + l * 16);
        }
        __syncthreads();
        const unsigned short* hf = (const unsigned short*)s_h[0];
        if (tid < 160) {
            int row = tid / 10, cls = tid - row * 10;
            float s = fcb[cls];
            const float* wrow = fcw + cls * 256;
            for (int k = 0; k < 256; ++k)
                s += b2f(hf[fidx(row, k)]) * wrow[k];
            out[(b0 + row) * 10 + cls] = s;
        }
    }
}

// ---------------- fallback (ws too small): R3 32-block kernel ----------------
#define FB_LDS_WHN  0
#define FB_LDS_H    131072
#define FB_LDS_X    147456
#define FB_LDS_SIZE 151552

extern "C" __global__ void __launch_bounds__(512, 2)
gru_fb(const float* __restrict__ x, const float* __restrict__ Wx,
       const float* __restrict__ Wh, const float* __restrict__ bias,
       const float* __restrict__ fcw, const float* __restrict__ fcb,
       float* __restrict__ out)
{
    extern __shared__ char lds[];
    v8s* whn = (v8s*)(lds + FB_LDS_WHN);
    char* hl = lds + FB_LDS_H;
    char* xl = lds + FB_LDS_X;
    const int tid = threadIdx.x;
    const int w = tid >> 6, l = tid & 63;
    const int cl = l & 15, kg = l >> 4;
    const int b0 = blockIdx.x << 4;
    const int tiles[6] = {2*w, 2*w+1, 16+2*w, 17+2*w, 32+2*w, 33+2*w};

    for (int f = w; f < 128; f += 8) {
        int t5 = f >> 3, ks = f & 7;
        const float* src = Wh + (size_t)(512 + t5*16 + cl)*256 + ks*32 + kg*8;
        whn[f*64 + l] = cvt8(*(const f32x4*)src, *(const f32x4*)(src + 4));
    }
    v8s whB[4][8];
#pragma unroll
    for (int tt = 0; tt < 4; ++tt) {
        const float* src = Wh + (size_t)(tiles[tt]*16 + cl)*256 + kg*8;
#pragma unroll
        for (int ks = 0; ks < 8; ++ks)
            whB[tt][ks] = cvt8(*(const f32x4*)(src + ks*32), *(const f32x4*)(src + ks*32 + 4));
    }
    float brv[2], bzv[2], bhv[2];
#pragma unroll
    for (int p = 0; p < 2; ++p) {
        int ch = (w << 5) + (p << 4) + cl;
        brv[p] = bias[ch] * LOG2E; bzv[p] = bias[256+ch] * LOG2E;
        bhv[p] = bias[512+ch] * (2.0f * LOG2E);
    }
    for (int i = tid; i < 2048; i += 512) ((unsigned int*)hl)[i] = 0u;
    const int xr = tid >> 5, xc = (tid & 31) << 1;
    const int xidx = fidx(xr, xc);
    const float* xp = x + (((size_t)(b0 + xr)) << 16) + xc;
    {
        unsigned int pk = (unsigned int)f2b(xp[0]) | ((unsigned int)f2b(xp[1]) << 16);
        *(unsigned int*)(xl + xidx*2) = pk;
    }
    xp += 64;
    const int wn0 = (2*w)*8, wn1 = (2*w+1)*8;

    for (int t = 0; t < 1024; ++t) {
        __syncthreads();
        const int cur = t & 1;
        const v8s* hb = (const v8s*)(hl + cur*8192);
        const v8s* xb = (const v8s*)(xl + cur*2048);
        float xv0 = 0.0f, xv1 = 0.0f;
        if (t < 1023) { xv0 = xp[0]; xv1 = xp[1]; xp += 64; }
        v8s wxr[12];
#pragma unroll
        for (int tt = 0; tt < 6; ++tt) {
            float s = (tt < 4) ? LOG2E : 2.0f * LOG2E;
            const float* s0 = Wx + (size_t)(tiles[tt]*16 + cl)*64 + kg*8;
            wxr[tt*2]   = wfrag(s0, s);
            wxr[tt*2+1] = wfrag(s0 + 32, s);
        }
        f32x4 acc[8];
#pragma unroll
        for (int i = 0; i < 8; ++i) acc[i] = f32x4{0,0,0,0};
        // scale r/z Wh contributions happen via unscaled whB; rescale below
#pragma unroll
        for (int ks = 0; ks < 8; ++ks) {
            v8s a = hb[(ks << 6) + l];
            v8s n0 = whn[(wn0 + ks)*64 + l];
            v8s n1 = whn[(wn1 + ks)*64 + l];
            acc[0] = MF(a, whB[0][ks], acc[0]);
            acc[1] = MF(a, whB[1][ks], acc[1]);
            acc[2] = MF(a, whB[2][ks], acc[2]);
            acc[3] = MF(a, whB[3][ks], acc[3]);
            acc[4] = MF(a, n0, acc[4]);
            acc[5] = MF(a, n1, acc[5]);
        }
#pragma unroll
        for (int k2 = 0; k2 < 2; ++k2) {
            v8s ax = xb[(k2 << 6) + l];
            acc[0] = MF(ax, wxr[0+k2], acc[0]);
            acc[1] = MF(ax, wxr[2+k2], acc[1]);
            acc[2] = MF(ax, wxr[4+k2], acc[2]);
            acc[3] = MF(ax, wxr[6+k2], acc[3]);
            acc[6] = MF(ax, wxr[8+k2], acc[6]);
            acc[7] = MF(ax, wxr[10+k2], acc[7]);
        }
        const unsigned short* hc16 = (const unsigned short*)hb;
        unsigned short* hn16 = (unsigned short*)(hl + ((cur ^ 1) * 8192));
#pragma unroll
        for (int p = 0; p < 2; ++p) {
            int ch = (w << 5) + (p << 4) + cl;
            int chbase = ((ch >> 5) << 9) + (((ch >> 3) & 3) << 7) + (ch & 7);
#pragma unroll
            for (int i = 0; i < 4; ++i) {
                int row = (kg << 2) + i;
                int idx = chbase + (row << 3);
                // whB r/z are unscaled; x-part scaled. Mixed — rescale h-part here.
                float rg = sg(acc[p][i] * LOG2E + brv[p] + 0.0f);
                float zg = sg(acc[2+p][i] * LOG2E + bzv[p]);
                float nv = acc[6+p][i] + bhv[p] + rg * (acc[4+p][i] * (2.0f * LOG2E));
                float ng = __builtin_fmaf(2.0f, sg(nv), -1.0f);
                float hold = b2f(hc16[idx]);
                float hy = ng + zg * (hold - ng);
                hn16[idx] = f2b(hy);
            }
        }
        if (t < 1023) {
            unsigned int pk = (unsigned int)f2b(xv0) | ((unsigned int)f2b(xv1) << 16);
            *(unsigned int*)(xl + ((cur ^ 1) * 2048) + xidx*2) = pk;
        }
    }
    __syncthreads();
    const unsigned short* hf = (const unsigned short*)hl;
    if (tid < 160) {
        int row = tid / 10, cls = tid - row * 10;
        float s = fcb[cls];
        const float* wrow = fcw + cls * 256;
        for (int k = 0; k < 256; ++k)
            s += b2f(hf[fidx(row, k)]) * wrow[k];
        out[(b0 + row)*10 + cls] = s;
    }
}

extern "C" void kernel_launch(void* const* d_in, const int* in_sizes, int n_in,
                              void* d_out, int out_size, void* d_ws, size_t ws_size,
                              hipStream_t stream) {
    const float* x    = (const float*)d_in[0];
    const float* Wx   = (const float*)d_in[1];
    const float* Wh   = (const float*)d_in[2];
    const float* bias = (const float*)d_in[3];
    const float* fcw  = (const float*)d_in[4];
    const float* fcb  = (const float*)d_in[5];

    if (ws_size >= (size_t)WS_NEED) {
        gru_pair<<<dim3(64), dim3(512), 0, stream>>>(
            x, Wx, Wh, bias, fcw, fcb, (float*)d_out, (char*)d_ws);
    } else {
        (void)hipFuncSetAttribute((const void*)gru_fb,
                                  hipFuncAttributeMaxDynamicSharedMemorySize, FB_LDS_SIZE);
        gru_fb<<<dim3(32), dim3(512), FB_LDS_SIZE, stream>>>(
            x, Wx, Wh, bias, fcw, fcb, (float*)d_out);
    }
}

// Round 5
// 2034.131 us; speedup vs baseline: 1.8767x; 1.8767x over previous
//
#include <hip/hip_runtime.h>
#include <hip/hip_fp16.h>

// R5: prepass computes gate_x = (x@Wx^T + b) pre-scaled (log2e; 2log2e for n)
// as fp16 [S][B][768] in d_ws using all 256 CUs. The 32-block persistent scan
// then runs a pure Wh recurrence: 384 MFMA/CU-step (floor 1865 cyc), zero
// per-step weight VMEM, gx via 24 imm-offset ushort loads/lane hidden under
// the MFMA phase, hprev in registers. Regs ~215 < 256 (no spill).

typedef short v8s __attribute__((ext_vector_type(8)));   // 8 bf16
typedef float f32x4 __attribute__((ext_vector_type(4)));

#define LOG2E 1.4426950408889634f
#define GX_ELEMS (512ull * 1024ull * 768ull)
#define WS_NEED (GX_ELEMS * 2ull)          // 805,306,368 B fp16

__device__ __forceinline__ unsigned short f2b(float f) {
    unsigned int u = __float_as_uint(f);
    u += 0x7FFFu + ((u >> 16) & 1u);       // RNE
    return (unsigned short)(u >> 16);
}
__device__ __forceinline__ float b2f(unsigned short h) {
    return __uint_as_float(((unsigned int)h) << 16);
}
__device__ __forceinline__ v8s cvt8(f32x4 a, f32x4 b) {
    v8s r;
#pragma unroll
    for (int j = 0; j < 4; ++j) { r[j] = (short)f2b(a[j]); r[4 + j] = (short)f2b(b[j]); }
    return r;
}
__device__ __forceinline__ v8s wfrag(const float* src, float s) {
    f32x4 a = *(const f32x4*)src, b = *(const f32x4*)(src + 4);
    a *= s; b *= s;
    return cvt8(a, b);
}
__device__ __forceinline__ float rcpf(float v) {
#if __has_builtin(__builtin_amdgcn_rcpf)
    return __builtin_amdgcn_rcpf(v);
#else
    return 1.0f / v;
#endif
}
__device__ __forceinline__ float exp2f_(float v) {
#if __has_builtin(__builtin_amdgcn_exp2f)
    return __builtin_amdgcn_exp2f(v);
#else
    return __exp2f(v);
#endif
}
// sigmoid of log2e-scaled preactivation
__device__ __forceinline__ float sg(float v) { return rcpf(1.0f + exp2f_(-v)); }
// unscaled (fallback)
__device__ __forceinline__ float sigm(float v) {
    float e = __expf(-fmaxf(v, -30.0f));
    return rcpf(1.0f + e);
}
__device__ __forceinline__ float tanh_(float v) {
    float vc = fmaxf(fminf(v, 30.0f), -30.0f);
    float e = __expf(-2.0f * vc);
    return (1.0f - e) * rcpf(1.0f + e);
}
__device__ __forceinline__ f32x4 MF(v8s a, v8s b, f32x4 c) {
    return __builtin_amdgcn_mfma_f32_16x16x32_bf16(a, b, c, 0, 0, 0);
}
// A-frag order index for element (row, k): u16 units
__device__ __forceinline__ int fidx(int row, int k) {
    return ((k >> 5) << 9) + ((((k >> 3) & 3) << 4) + row) * 8 + (k & 7);
}

// ======================= prepass: gate_x =======================
// grid 2048 = (g = b&31, tc = b>>5); block: 16 batch rows x 16 timesteps x 768.
extern "C" __global__ void __launch_bounds__(512)
gx_prepass(const float* __restrict__ x, const float* __restrict__ Wx,
           const float* __restrict__ bias, __half* __restrict__ gx)
{
    extern __shared__ char plds[];
    v8s* wxf = (v8s*)plds;                 // 96 frags * 64 lanes * 16B = 96KB

    const int tid = threadIdx.x;
    const int w = tid >> 6, l = tid & 63;
    const int cl = l & 15, kg = l >> 4;
    const int g = blockIdx.x & 31, tc = blockIdx.x >> 5;
    const int b0 = g << 4;

    // stage scaled Wx B-frags
    for (int fid = w; fid < 96; fid += 8) {
        int ct = fid >> 1, k2 = fid & 1;
        float sc = (ct < 32) ? LOG2E : 2.0f * LOG2E;
        const float* src = Wx + (size_t)(ct * 16 + cl) * 64 + k2 * 32 + kg * 8;
        wxf[fid * 64 + l] = wfrag(src, sc);
    }
    __syncthreads();

    const int tiles[6] = {2*w, 2*w+1, 16+2*w, 17+2*w, 32+2*w, 33+2*w};
    float bv[6];
#pragma unroll
    for (int tt = 0; tt < 6; ++tt)
        bv[tt] = bias[tiles[tt] * 16 + cl] * ((tt < 4) ? LOG2E : 2.0f * LOG2E);

    for (int t16 = 0; t16 < 16; ++t16) {
        const int t = tc * 16 + t16;
        const float* xs = x + ((size_t)(b0 + cl) * 1024 + t) * 64 + kg * 8;
        v8s a0 = cvt8(*(const f32x4*)xs,        *(const f32x4*)(xs + 4));
        v8s a1 = cvt8(*(const f32x4*)(xs + 32), *(const f32x4*)(xs + 36));

        f32x4 acc[6];
#pragma unroll
        for (int tt = 0; tt < 6; ++tt) {
            acc[tt] = f32x4{0, 0, 0, 0};
            acc[tt] = MF(a0, wxf[(tiles[tt] * 2) * 64 + l], acc[tt]);
            acc[tt] = MF(a1, wxf[(tiles[tt] * 2 + 1) * 64 + l], acc[tt]);
        }
        const size_t rbase = (size_t)t * 512 + b0 + (kg << 2);
#pragma unroll
        for (int tt = 0; tt < 6; ++tt)
#pragma unroll
            for (int i = 0; i < 4; ++i)
                gx[(rbase + i) * 768 + tiles[tt] * 16 + cl] =
                    __float2half_rn(acc[tt][i] + bv[tt]);
    }
}

// ======================= scan: pure Wh recurrence =======================
#define S_LDS_WHN  0           // 16 tiles * 8 ks * 1KB = 131072
#define S_LDS_H    131072      // 2 * 8192 ping-pong
#define S_LDS_SIZE 147456

extern "C" __global__ void __launch_bounds__(512, 2)
gru_scan2(const float* __restrict__ Wh, const __half* __restrict__ gx,
          const float* __restrict__ fcw, const float* __restrict__ fcb,
          float* __restrict__ out)
{
    extern __shared__ char lds[];
    v8s* whn = (v8s*)(lds + S_LDS_WHN);
    char* hl = lds + S_LDS_H;

    const int tid = threadIdx.x;
    const int w = tid >> 6, l = tid & 63;
    const int cl = l & 15, kg = l >> 4;
    const int b0 = blockIdx.x << 4;

    // n-gate Wh (tiles 32..47) -> LDS frags, scaled 2log2e
    for (int f = w; f < 128; f += 8) {
        int t5 = f >> 3, ks = f & 7;
        const float* src = Wh + (size_t)(512 + t5 * 16 + cl) * 256 + ks * 32 + kg * 8;
        whn[f * 64 + l] = wfrag(src, 2.0f * LOG2E);
    }
    // r+z Wh resident, scaled log2e: exactly 128 regs
    v8s whB[4][8];
#pragma unroll
    for (int tt = 0; tt < 4; ++tt) {
        const int tv = (tt < 2) ? (2 * w + tt) : (16 + 2 * w + (tt - 2));
        const float* src = Wh + (size_t)(tv * 16 + cl) * 256 + kg * 8;
#pragma unroll
        for (int ks = 0; ks < 8; ++ks)
            whB[tt][ks] = wfrag(src + ks * 32, LOG2E);
    }

    // h0 = 0 (buffer 0)
    for (int i = tid; i < 2048; i += 512) ((unsigned int*)hl)[i] = 0u;
    float hprev[8] = {0, 0, 0, 0, 0, 0, 0, 0};
    const int wn0 = (2 * w) * 8, wn1 = (2 * w + 1) * 8;
    const __half* gq = gx + (size_t)(b0 + (kg << 2)) * 768 + w * 32 + cl;

    for (int t = 0; t < 1024; ++t) {
        __syncthreads();
        const int cur = t & 1;
        const v8s* hb = (const v8s*)(hl + cur * 8192);

        // gx loads: one base VGPR + 24 immediate offsets; consumed ~1900cyc later
        __half gxv[24];
#pragma unroll
        for (int gate = 0; gate < 3; ++gate)
#pragma unroll
            for (int p = 0; p < 2; ++p)
#pragma unroll
                for (int i = 0; i < 4; ++i)
                    gxv[gate * 8 + p * 4 + i] = gq[gate * 256 + p * 16 + i * 768];
        gq += 393216;   // next t

        f32x4 aR[2] = {{0,0,0,0},{0,0,0,0}}, aZ[2] = {{0,0,0,0},{0,0,0,0}},
              aN[2] = {{0,0,0,0},{0,0,0,0}};
#pragma unroll
        for (int ks = 0; ks < 8; ++ks) {
            v8s a  = hb[(ks << 6) + l];
            v8s n0 = whn[(wn0 + ks) * 64 + l];
            v8s n1 = whn[(wn1 + ks) * 64 + l];
            aR[0] = MF(a, whB[0][ks], aR[0]);
            aR[1] = MF(a, whB[1][ks], aR[1]);
            aZ[0] = MF(a, whB[2][ks], aZ[0]);
            aZ[1] = MF(a, whB[3][ks], aZ[1]);
            aN[0] = MF(a, n0, aN[0]);
            aN[1] = MF(a, n1, aN[1]);
        }

        unsigned short* hn = (unsigned short*)(hl + (cur ^ 1) * 8192);
#pragma unroll
        for (int p = 0; p < 2; ++p) {
            const int ch = w * 32 + p * 16 + cl;
            const int chbase = ((ch >> 5) << 9) + (((ch >> 3) & 3) << 7) + (ch & 7);
#pragma unroll
            for (int i = 0; i < 4; ++i) {
                float rg = sg(aR[p][i] + __half2float(gxv[p * 4 + i]));
                float zg = sg(aZ[p][i] + __half2float(gxv[8 + p * 4 + i]));
                float nv = __builtin_fmaf(rg, aN[p][i], __half2float(gxv[16 + p * 4 + i]));
                float ng = __builtin_fmaf(2.0f, sg(nv), -1.0f);
                float hy = ng + zg * (hprev[p * 4 + i] - ng);
                hprev[p * 4 + i] = hy;
                hn[chbase + ((kg << 2) + i) * 8] = f2b(hy);
            }
        }
    }

    __syncthreads();
    // logits from hT (buffer 0)
    const unsigned short* hf = (const unsigned short*)hl;
    if (tid < 160) {
        int row = tid / 10, cls = tid - row * 10;
        float s = fcb[cls];
        const float* wrow = fcw + cls * 256;
        for (int k = 0; k < 256; ++k)
            s += b2f(hf[fidx(row, k)]) * wrow[k];
        out[(b0 + row) * 10 + cls] = s;
    }
}

// ================= fallback (ws too small): R3 kernel, unscaled =================
#define FB_LDS_SIZE 151552
extern "C" __global__ void __launch_bounds__(512, 2)
gru_fb(const float* __restrict__ x, const float* __restrict__ Wx,
       const float* __restrict__ Wh, const float* __restrict__ bias,
       const float* __restrict__ fcw, const float* __restrict__ fcb,
       float* __restrict__ out)
{
    extern __shared__ char lds[];
    v8s* whn = (v8s*)lds;
    char* hl = lds + 131072;
    char* xl = lds + 147456;
    const int tid = threadIdx.x;
    const int w = tid >> 6, l = tid & 63;
    const int cl = l & 15, kg = l >> 4;
    const int b0 = blockIdx.x << 4;
    const int tiles[6] = {2*w, 2*w+1, 16+2*w, 17+2*w, 32+2*w, 33+2*w};

    for (int f = w; f < 128; f += 8) {
        int t5 = f >> 3, ks = f & 7;
        const float* src = Wh + (size_t)(512 + t5*16 + cl)*256 + ks*32 + kg*8;
        whn[f*64 + l] = wfrag(src, 1.0f);
    }
    v8s whB[4][8];
#pragma unroll
    for (int tt = 0; tt < 4; ++tt) {
        const float* src = Wh + (size_t)(tiles[tt]*16 + cl)*256 + kg*8;
#pragma unroll
        for (int ks = 0; ks < 8; ++ks)
            whB[tt][ks] = wfrag(src + ks*32, 1.0f);
    }
    float brv[2], bzv[2], bhv[2];
#pragma unroll
    for (int p = 0; p < 2; ++p) {
        int ch = (w << 5) + (p << 4) + cl;
        brv[p] = bias[ch]; bzv[p] = bias[256+ch]; bhv[p] = bias[512+ch];
    }
    for (int i = tid; i < 2048; i += 512) ((unsigned int*)hl)[i] = 0u;
    const int xr = tid >> 5, xc = (tid & 31) << 1;
    const int xidx = fidx(xr, xc);
    const float* xp = x + (((size_t)(b0 + xr)) << 16) + xc;
    {
        unsigned int pk = (unsigned int)f2b(xp[0]) | ((unsigned int)f2b(xp[1]) << 16);
        *(unsigned int*)(xl + xidx*2) = pk;
    }
    xp += 64;
    const int wn0 = (2*w)*8, wn1 = (2*w+1)*8;

    for (int t = 0; t < 1024; ++t) {
        __syncthreads();
        const int cur = t & 1;
        const v8s* hb = (const v8s*)(hl + cur*8192);
        const v8s* xb = (const v8s*)(xl + cur*2048);
        float xv0 = 0.0f, xv1 = 0.0f;
        if (t < 1023) { xv0 = xp[0]; xv1 = xp[1]; xp += 64; }
        v8s wxr[12];
#pragma unroll
        for (int tt = 0; tt < 6; ++tt) {
            const float* s0 = Wx + (size_t)(tiles[tt]*16 + cl)*64 + kg*8;
            wxr[tt*2]   = wfrag(s0, 1.0f);
            wxr[tt*2+1] = wfrag(s0 + 32, 1.0f);
        }
        f32x4 acc[8];
#pragma unroll
        for (int i = 0; i < 8; ++i) acc[i] = f32x4{0,0,0,0};
#pragma unroll
        for (int ks = 0; ks < 8; ++ks) {
            v8s a = hb[(ks << 6) + l];
            v8s n0 = whn[(wn0 + ks)*64 + l];
            v8s n1 = whn[(wn1 + ks)*64 + l];
            acc[0] = MF(a, whB[0][ks], acc[0]);
            acc[1] = MF(a, whB[1][ks], acc[1]);
            acc[2] = MF(a, whB[2][ks], acc[2]);
            acc[3] = MF(a, whB[3][ks], acc[3]);
            acc[4] = MF(a, n0, acc[4]);
            acc[5] = MF(a, n1, acc[5]);
        }
#pragma unroll
        for (int k2 = 0; k2 < 2; ++k2) {
            v8s ax = xb[(k2 << 6) + l];
            acc[0] = MF(ax, wxr[0+k2], acc[0]);
            acc[1] = MF(ax, wxr[2+k2], acc[1]);
            acc[2] = MF(ax, wxr[4+k2], acc[2]);
            acc[3] = MF(ax, wxr[6+k2], acc[3]);
            acc[6] = MF(ax, wxr[8+k2], acc[6]);
            acc[7] = MF(ax, wxr[10+k2], acc[7]);
        }
        const unsigned short* hc16 = (const unsigned short*)hb;
        unsigned short* hn16 = (unsigned short*)(hl + ((cur ^ 1) * 8192));
#pragma unroll
        for (int p = 0; p < 2; ++p) {
            int ch = (w << 5) + (p << 4) + cl;
            int chbase = ((ch >> 5) << 9) + (((ch >> 3) & 3) << 7) + (ch & 7);
#pragma unroll
            for (int i = 0; i < 4; ++i) {
                int row = (kg << 2) + i;
                int idx = chbase + (row << 3);
                float rg = sigm(acc[p][i] + brv[p]);
                float zg = sigm(acc[2+p][i] + bzv[p]);
                float ng = tanh_(acc[6+p][i] + bhv[p] + rg * acc[4+p][i]);
                float hold = b2f(hc16[idx]);
                float hy = ng + zg * (hold - ng);
                hn16[idx] = f2b(hy);
            }
        }
        if (t < 1023) {
            unsigned int pk = (unsigned int)f2b(xv0) | ((unsigned int)f2b(xv1) << 16);
            *(unsigned int*)(xl + ((cur ^ 1) * 2048) + xidx*2) = pk;
        }
    }
    __syncthreads();
    const unsigned short* hf = (const unsigned short*)hl;
    if (tid < 160) {
        int row = tid / 10, cls = tid - row * 10;
        float s = fcb[cls];
        const float* wrow = fcw + cls * 256;
        for (int k = 0; k < 256; ++k)
            s += b2f(hf[fidx(row, k)]) * wrow[k];
        out[(b0 + row)*10 + cls] = s;
    }
}

extern "C" void kernel_launch(void* const* d_in, const int* in_sizes, int n_in,
                              void* d_out, int out_size, void* d_ws, size_t ws_size,
                              hipStream_t stream) {
    const float* x    = (const float*)d_in[0];
    const float* Wx   = (const float*)d_in[1];
    const float* Wh   = (const float*)d_in[2];
    const float* bias = (const float*)d_in[3];
    const float* fcw  = (const float*)d_in[4];
    const float* fcb  = (const float*)d_in[5];

    if (ws_size >= WS_NEED) {
        (void)hipFuncSetAttribute((const void*)gx_prepass,
                                  hipFuncAttributeMaxDynamicSharedMemorySize, 98304);
        (void)hipFuncSetAttribute((const void*)gru_scan2,
                                  hipFuncAttributeMaxDynamicSharedMemorySize, S_LDS_SIZE);
        gx_prepass<<<dim3(2048), dim3(512), 98304, stream>>>(
            x, Wx, bias, (__half*)d_ws);
        gru_scan2<<<dim3(32), dim3(512), S_LDS_SIZE, stream>>>(
            Wh, (const __half*)d_ws, fcw, fcb, (float*)d_out);
    } else {
        (void)hipFuncSetAttribute((const void*)gru_fb,
                                  hipFuncAttributeMaxDynamicSharedMemorySize, FB_LDS_SIZE);
        gru_fb<<<dim3(32), dim3(512), FB_LDS_SIZE, stream>>>(
            x, Wx, Wh, bias, fcw, fcb, (float*)d_out);
    }
}